// Round 8
// baseline (370.926 us; speedup 1.0000x reference)
//
#include <hip/hip_runtime.h>
#include <hip/hip_bf16.h>

#define HC 256        // HEADS*OUT_CH
#define NEG_SLOPE 0.2f
#define BM 64
#define LDKF 264      // full-k padded LDS stride (bf16 elems): 528B rows, 16B-aligned

typedef short short8_t __attribute__((ext_vector_type(8)));
typedef float float4_t __attribute__((ext_vector_type(4)));
typedef int   int4_t   __attribute__((ext_vector_type(4)));

__device__ __forceinline__ unsigned short f2bf(float f) {
  unsigned u = __float_as_uint(f);
  return (unsigned short)((u + 0x7fffu + ((u >> 16) & 1u)) >> 16);  // RNE
}
__device__ __forceinline__ float bf2f(unsigned short b) {
  return __uint_as_float(((unsigned)b) << 16);
}

// ---------------------------------------------------------------------------
// D1: Wt[n][k] = bf16(W[k][n]) + zero deg (proven r7).
// ---------------------------------------------------------------------------
__global__ void wt_kernel(const float* __restrict__ W, unsigned short* __restrict__ Wt,
                          int* __restrict__ deg, int n)
{
  const int k = blockIdx.x;
  const int t = threadIdx.x;
  Wt[t * 256 + k] = f2bf(W[k * 256 + t]);
  const int i = k * 256 + t;
  if (i < n) deg[i] = 0;
}

// ---------------------------------------------------------------------------
// D2: FUSED gemm + deg histogram (independent workloads, block-range split).
// Blocks [0,NG): the r7 gemm (A staged once, B direct from L2-hot Wt).
// Blocks [NG,NG+ND): grid-stride degree histogram (needs only zeroed deg).
// No synchronization between the two halves is needed; fusing removes one
// full dispatch boundary from the serialized 8-dispatch chain.
// ---------------------------------------------------------------------------
__global__ __launch_bounds__(256) void gemm_deg(
    const float* __restrict__ x, const unsigned short* __restrict__ Wt,
    const float* __restrict__ att_src, const float* __restrict__ att_dst,
    unsigned short* __restrict__ h, float* __restrict__ a_src,
    float* __restrict__ a_dst, int nnodes,
    const int* __restrict__ ei, int* __restrict__ deg, int E, int NG, int ND)
{
  __shared__ unsigned short As[BM * LDKF];   // 33792 B (gemm path only)
  const int t = threadIdx.x;

  if (blockIdx.x >= NG) {
    // ---- histogram path ----
    const int b = blockIdx.x - NG;
    for (int e = b * 256 + t; e < E; e += ND * 256)
      atomicAdd(&deg[ei[E + e]], 1);
    return;
  }

  // ---- gemm path (byte-identical logic to r7, proven) ----
  const int wv   = t >> 6;
  const int lane = t & 63;
  const int r0   = blockIdx.x * BM;

  {
    const int row = t >> 2, kcb = (t & 3) * 16;
    const int gr = r0 + row;
    #pragma unroll
    for (int k0 = 0; k0 < 256; k0 += 64) {
      float4 xv[4];
      if (gr < nnodes) {
        const float4* p = (const float4*)(x + (size_t)gr * 256 + k0 + kcb);
        xv[0] = p[0]; xv[1] = p[1]; xv[2] = p[2]; xv[3] = p[3];
      } else {
        xv[0] = xv[1] = xv[2] = xv[3] = make_float4(0.f, 0.f, 0.f, 0.f);
      }
      const float* f = (const float*)xv;
      unsigned pk[8];
      #pragma unroll
      for (int i = 0; i < 8; ++i) {
        __hip_bfloat162 b2 = __float22bfloat162_rn(make_float2(f[2 * i], f[2 * i + 1]));
        pk[i] = *(unsigned*)&b2;
      }
      uint4* d = (uint4*)&As[row * LDKF + k0 + kcb];
      d[0] = make_uint4(pk[0], pk[1], pk[2], pk[3]);
      d[1] = make_uint4(pk[4], pk[5], pk[6], pk[7]);
    }
  }
  __syncthreads();

  const int l15 = lane & 15, q = lane >> 4;
  float4_t acc[4][4] = {};   // [mt][nt]

  const unsigned short* __restrict__ Bp = Wt + ((size_t)(64 * wv + l15)) * 256 + q * 8;

  #pragma unroll
  for (int kstep = 0; kstep < 8; ++kstep) {
    const int ko = kstep * 32;
    short8_t bfr[4], af[4];
    #pragma unroll
    for (int nt = 0; nt < 4; ++nt)
      bfr[nt] = *(const short8_t*)(Bp + nt * 16 * 256 + ko);
    #pragma unroll
    for (int mt = 0; mt < 4; ++mt)
      af[mt] = *(const short8_t*)&As[(16 * mt + l15) * LDKF + ko + q * 8];
    #pragma unroll
    for (int mt = 0; mt < 4; ++mt)
      #pragma unroll
      for (int nt = 0; nt < 4; ++nt)
        acc[mt][nt] = __builtin_amdgcn_mfma_f32_16x16x32_bf16(
            af[mt], bfr[nt], acc[mt][nt], 0, 0, 0);
  }

  float atts[4], attd[4];
  #pragma unroll
  for (int nt = 0; nt < 4; ++nt) {
    atts[nt] = att_src[wv * 64 + 16 * nt + l15];
    attd[nt] = att_dst[wv * 64 + 16 * nt + l15];
  }

  #pragma unroll
  for (int mt = 0; mt < 4; ++mt) {
    #pragma unroll
    for (int reg = 0; reg < 4; ++reg) {
      const int row = r0 + 16 * mt + 4 * q + reg;
      const bool ok = row < nnodes;
      float ps = 0.f, pd = 0.f;
      #pragma unroll
      for (int nt = 0; nt < 4; ++nt) {
        const float v = acc[mt][nt][reg];
        if (ok) h[(size_t)row * 256 + 64 * wv + 16 * nt + l15] = f2bf(v);
        ps += v * atts[nt];
        pd += v * attd[nt];
      }
      #pragma unroll
      for (int off = 8; off; off >>= 1) {
        ps += __shfl_down(ps, off, 16);
        pd += __shfl_down(pd, off, 16);
      }
      if (ok && l15 == 0) {
        a_src[row * 4 + wv] = ps;
        a_dst[row * 4 + wv] = pd;
      }
    }
  }
}

// ---------------------------------------------------------------------------
// D3: scan_all — single-block exclusive scan of deg -> rowptr, cursor.
// (round-3 version, correctness-proven there; replaces 3 scan dispatches.)
// ---------------------------------------------------------------------------
__global__ __launch_bounds__(1024) void scan_all(
    const int* __restrict__ deg, int* __restrict__ rowptr,
    int* __restrict__ cursor, int n)
{
  __shared__ int wsum[16], woff[16];
  const int t = threadIdx.x, lane = t & 63, wv = t >> 6;
  const int C = (n + 1023) / 1024;
  const int lo = t * C, hi = min(lo + C, n);

  int s = 0;
  for (int i = lo; i < hi; ++i) s += deg[i];

  int sc = s;
  #pragma unroll
  for (int off = 1; off < 64; off <<= 1) {
    int u = __shfl_up(sc, off, 64);
    if (lane >= off) sc += u;
  }
  if (lane == 63) wsum[wv] = sc;
  __syncthreads();
  if (t == 0) {
    int run = 0;
    #pragma unroll
    for (int i = 0; i < 16; ++i) { int x = wsum[i]; woff[i] = run; run += x; }
    rowptr[n] = run;
  }
  __syncthreads();

  int run = woff[wv] + (sc - s);   // exclusive prefix for this thread's chunk
  for (int i = lo; i < hi; ++i) {
    const int dg = deg[i];
    rowptr[i] = run; cursor[i] = run;
    run += dg;
  }
}

// ---------------------------------------------------------------------------
// D4: fill_csr, XCD-grouped, index-only (proven r5/r7).
// ---------------------------------------------------------------------------
__global__ __launch_bounds__(256) void fill_csr(
    const int* __restrict__ ei, int* __restrict__ cursor,
    int* __restrict__ csr_src, int E, int nnodes)
{
  const int g    = blockIdx.x & 7;
  const int bg   = blockIdx.x >> 3;
  const int nbg  = gridDim.x >> 3;
  const int gsz  = (nnodes + 7) >> 3;
  const int dlo  = g * gsz;
  const int dhi  = min(dlo + gsz, nnodes);

  for (int e = bg * 256 + threadIdx.x; e < E; e += nbg * 256) {
    const int d = ei[E + e];
    if (d < dlo || d >= dhi) continue;
    const int pos = atomicAdd(&cursor[d], 1);
    csr_src[pos] = ei[e];
  }
}

// ---------------------------------------------------------------------------
// D5: gather (byte-identical to r5/r7 proven version).
// ---------------------------------------------------------------------------
__device__ __forceinline__ float4 ld_h(const unsigned short* __restrict__ h,
                                       int row, int cb)
{
  const ushort4 u = *(const ushort4*)&h[(size_t)row * 256 + cb];
  return make_float4(bf2f(u.x), bf2f(u.y), bf2f(u.z), bf2f(u.w));
}

__device__ __forceinline__ float edge_w(float as, float ad)
{
  float al = as + ad;
  al = al > 0.f ? al : NEG_SLOPE * al;
  return expf(al);
}

__global__ __launch_bounds__(256) void gather_kernel(
    const int* __restrict__ rowptr, const int* __restrict__ csr_src,
    const unsigned short* __restrict__ h,
    const float* __restrict__ a_src, const float* __restrict__ a_dst,
    const float* __restrict__ bias, float* __restrict__ out, int n)
{
  const int wave = threadIdx.x >> 6;
  const int lane = threadIdx.x & 63;
  const int d = blockIdx.x * 4 + wave;
  if (d >= n) return;

  const int head = lane >> 4;
  const int cb   = lane * 4;

  const float ad = a_dst[d * 4 + head];

  const float w = edge_w(a_src[d * 4 + head], ad);
  float dsum = w;
  float4 hv = ld_h(h, d, cb);
  float4 acc = make_float4(w * hv.x, w * hv.y, w * hv.z, w * hv.w);

  int j = rowptr[d];
  const int end = rowptr[d + 1];

  int4_t sC = {0, 0, 0, 0};
  if (j + 3 < end)
    sC = __builtin_nontemporal_load((const int4_t*)&csr_src[j]);
  while (j + 3 < end) {
    const int jn = j + 4;
    const int jp = (jn + 3 < end) ? jn : j;   // clamp: reload current on last iter
    const int4_t sN = __builtin_nontemporal_load((const int4_t*)&csr_src[jp]);

    const float as0 = a_src[sC.x * 4 + head];
    const float as1 = a_src[sC.y * 4 + head];
    const float as2 = a_src[sC.z * 4 + head];
    const float as3 = a_src[sC.w * 4 + head];
    const float4 h0 = ld_h(h, sC.x, cb);
    const float4 h1 = ld_h(h, sC.y, cb);
    const float4 h2 = ld_h(h, sC.z, cb);
    const float4 h3 = ld_h(h, sC.w, cb);

    const float w0 = edge_w(as0, ad);
    const float w1 = edge_w(as1, ad);
    const float w2 = edge_w(as2, ad);
    const float w3 = edge_w(as3, ad);

    dsum += (w0 + w1) + (w2 + w3);
    acc.x += w0 * h0.x + w1 * h1.x + w2 * h2.x + w3 * h3.x;
    acc.y += w0 * h0.y + w1 * h1.y + w2 * h2.y + w3 * h3.y;
    acc.z += w0 * h0.z + w1 * h1.z + w2 * h2.z + w3 * h3.z;
    acc.w += w0 * h0.w + w1 * h1.w + w2 * h2.w + w3 * h3.w;

    sC = sN; j = jn;
  }
  for (; j < end; ++j) {
    const int s0 = csr_src[j];
    const float w0 = edge_w(a_src[s0 * 4 + head], ad);
    const float4 h0 = ld_h(h, s0, cb);
    dsum += w0;
    acc.x += w0 * h0.x; acc.y += w0 * h0.y;
    acc.z += w0 * h0.z; acc.w += w0 * h0.w;
  }

  const float inv = 1.f / (dsum + 1e-16f);
  const float4 b4 = ((const float4*)bias)[lane];
  float4 o;
  o.x = acc.x * inv + b4.x; o.x = o.x > 0.f ? o.x : 0.f;
  o.y = acc.y * inv + b4.y; o.y = o.y > 0.f ? o.y : 0.f;
  o.z = acc.z * inv + b4.z; o.z = o.z > 0.f ? o.z : 0.f;
  o.w = acc.w * inv + b4.w; o.w = o.w > 0.f ? o.w : 0.f;
  *(float4*)&out[(size_t)d * 256 + cb] = o;
}

extern "C" void kernel_launch(void* const* d_in, const int* in_sizes, int n_in,
                              void* d_out, int out_size, void* d_ws, size_t ws_size,
                              hipStream_t stream)
{
  const float* x       = (const float*)d_in[0];
  const int*   ei      = (const int*)d_in[1];
  const float* W       = (const float*)d_in[2];
  const float* att_src = (const float*)d_in[3];
  const float* att_dst = (const float*)d_in[4];
  const float* bias    = (const float*)d_in[5];

  const int nnodes = in_sizes[0] / HC;   // 50000
  const int E      = in_sizes[1] / 2;    // 800000

  float* out = (float*)d_out;
  char* ws = (char*)d_ws;
  // Workspace (~30 MB), all segments 16B-aligned:
  unsigned short* h  = (unsigned short*)ws;                          // nnodes*256 bf16 (row-major)
  float* a_src = (float*)(ws + (size_t)nnodes * HC * 2);             // nnodes*4 f32
  float* a_dst = a_src + (size_t)nnodes * 4;
  unsigned short* Wt = (unsigned short*)(a_dst + (size_t)nnodes * 4); // 256*256 bf16
  int* deg    = (int*)((char*)Wt + 256 * 256 * 2);                   // nnodes
  int* rowptr = deg + nnodes;                                        // nnodes+1 (pad x4)
  int* cursor = rowptr + ((nnodes + 1 + 3) & ~3);                    // nnodes
  int* csr    = cursor + ((nnodes + 3) & ~3);                        // E

  const int NG = (nnodes + BM - 1) / BM;   // 782 gemm blocks
  const int ND = 1024;                     // histogram blocks

  // D1: W transpose + deg zeroing
  wt_kernel<<<256, 256, 0, stream>>>(W, Wt, deg, nnodes);

  // D2: fused projection GEMM + degree histogram (independent halves)
  gemm_deg<<<NG + ND, 256, 0, stream>>>(
      x, Wt, att_src, att_dst, h, a_src, a_dst, nnodes, ei, deg, E, NG, ND);

  // D3: single-block scan -> rowptr/cursor
  scan_all<<<1, 1024, 0, stream>>>(deg, rowptr, cursor, nnodes);

  // D4: CSR fill
  fill_csr<<<1024, 256, 0, stream>>>(ei, cursor, csr, E, nnodes);

  // D5: gather / softmax / output
  gather_kernel<<<(nnodes + 3) / 4, 256, 0, stream>>>(
      rowptr, csr, h, a_src, a_dst, bias, out, nnodes);
}

// Round 9
// 289.909 us; speedup vs baseline: 1.2795x; 1.2795x over previous
//
#include <hip/hip_runtime.h>
#include <hip/hip_bf16.h>

#define HC 256        // HEADS*OUT_CH
#define NEG_SLOPE 0.2f
#define BM 64
#define LDKF 264      // full-k padded LDS stride (bf16 elems): 528B rows, 16B-aligned

typedef short short8_t __attribute__((ext_vector_type(8)));
typedef float float4_t __attribute__((ext_vector_type(4)));
typedef int   int4_t   __attribute__((ext_vector_type(4)));

__device__ __forceinline__ unsigned short f2bf(float f) {
  unsigned u = __float_as_uint(f);
  return (unsigned short)((u + 0x7fffu + ((u >> 16) & 1u)) >> 16);  // RNE
}
__device__ __forceinline__ float bf2f(unsigned short b) {
  return __uint_as_float(((unsigned)b) << 16);
}

// ---------------------------------------------------------------------------
// D1: Wt[n][k] = bf16(W[k][n]) + zero deg (proven r7/r8).
// ---------------------------------------------------------------------------
__global__ void wt_kernel(const float* __restrict__ W, unsigned short* __restrict__ Wt,
                          int* __restrict__ deg, int n)
{
  const int k = blockIdx.x;
  const int t = threadIdx.x;
  Wt[t * 256 + k] = f2bf(W[k * 256 + t]);
  const int i = k * 256 + t;
  if (i < n) deg[i] = 0;
}

// ---------------------------------------------------------------------------
// D2: FUSED gemm + deg histogram (proven r8; dispatch-saving, neutral cost).
// ---------------------------------------------------------------------------
__global__ __launch_bounds__(256) void gemm_deg(
    const float* __restrict__ x, const unsigned short* __restrict__ Wt,
    const float* __restrict__ att_src, const float* __restrict__ att_dst,
    unsigned short* __restrict__ h, float* __restrict__ a_src,
    float* __restrict__ a_dst, int nnodes,
    const int* __restrict__ ei, int* __restrict__ deg, int E, int NG, int ND)
{
  __shared__ unsigned short As[BM * LDKF];   // 33792 B (gemm path only)
  const int t = threadIdx.x;

  if (blockIdx.x >= NG) {
    // ---- histogram path ----
    const int b = blockIdx.x - NG;
    for (int e = b * 256 + t; e < E; e += ND * 256)
      atomicAdd(&deg[ei[E + e]], 1);
    return;
  }

  // ---- gemm path (proven r7/r8) ----
  const int wv   = t >> 6;
  const int lane = t & 63;
  const int r0   = blockIdx.x * BM;

  {
    const int row = t >> 2, kcb = (t & 3) * 16;
    const int gr = r0 + row;
    #pragma unroll
    for (int k0 = 0; k0 < 256; k0 += 64) {
      float4 xv[4];
      if (gr < nnodes) {
        const float4* p = (const float4*)(x + (size_t)gr * 256 + k0 + kcb);
        xv[0] = p[0]; xv[1] = p[1]; xv[2] = p[2]; xv[3] = p[3];
      } else {
        xv[0] = xv[1] = xv[2] = xv[3] = make_float4(0.f, 0.f, 0.f, 0.f);
      }
      const float* f = (const float*)xv;
      unsigned pk[8];
      #pragma unroll
      for (int i = 0; i < 8; ++i) {
        __hip_bfloat162 b2 = __float22bfloat162_rn(make_float2(f[2 * i], f[2 * i + 1]));
        pk[i] = *(unsigned*)&b2;
      }
      uint4* d = (uint4*)&As[row * LDKF + k0 + kcb];
      d[0] = make_uint4(pk[0], pk[1], pk[2], pk[3]);
      d[1] = make_uint4(pk[4], pk[5], pk[6], pk[7]);
    }
  }
  __syncthreads();

  const int l15 = lane & 15, q = lane >> 4;
  float4_t acc[4][4] = {};   // [mt][nt]

  const unsigned short* __restrict__ Bp = Wt + ((size_t)(64 * wv + l15)) * 256 + q * 8;

  #pragma unroll
  for (int kstep = 0; kstep < 8; ++kstep) {
    const int ko = kstep * 32;
    short8_t bfr[4], af[4];
    #pragma unroll
    for (int nt = 0; nt < 4; ++nt)
      bfr[nt] = *(const short8_t*)(Bp + nt * 16 * 256 + ko);
    #pragma unroll
    for (int mt = 0; mt < 4; ++mt)
      af[mt] = *(const short8_t*)&As[(16 * mt + l15) * LDKF + ko + q * 8];
    #pragma unroll
    for (int mt = 0; mt < 4; ++mt)
      #pragma unroll
      for (int nt = 0; nt < 4; ++nt)
        acc[mt][nt] = __builtin_amdgcn_mfma_f32_16x16x32_bf16(
            af[mt], bfr[nt], acc[mt][nt], 0, 0, 0);
  }

  float atts[4], attd[4];
  #pragma unroll
  for (int nt = 0; nt < 4; ++nt) {
    atts[nt] = att_src[wv * 64 + 16 * nt + l15];
    attd[nt] = att_dst[wv * 64 + 16 * nt + l15];
  }

  #pragma unroll
  for (int mt = 0; mt < 4; ++mt) {
    #pragma unroll
    for (int reg = 0; reg < 4; ++reg) {
      const int row = r0 + 16 * mt + 4 * q + reg;
      const bool ok = row < nnodes;
      float ps = 0.f, pd = 0.f;
      #pragma unroll
      for (int nt = 0; nt < 4; ++nt) {
        const float v = acc[mt][nt][reg];
        if (ok) h[(size_t)row * 256 + 64 * wv + 16 * nt + l15] = f2bf(v);
        ps += v * atts[nt];
        pd += v * attd[nt];
      }
      #pragma unroll
      for (int off = 8; off; off >>= 1) {
        ps += __shfl_down(ps, off, 16);
        pd += __shfl_down(pd, off, 16);
      }
      if (ok && l15 == 0) {
        a_src[row * 4 + wv] = ps;
        a_dst[row * 4 + wv] = pd;
      }
    }
  }
}

// ---------------------------------------------------------------------------
// D3-D5: 3-phase scan (REVERTED to proven r7 versions; scan_all was 110us,
// these three total ~15us incl. boundaries per r7<->r8 arithmetic).
// ---------------------------------------------------------------------------
__global__ __launch_bounds__(256) void scan_p1(const int* __restrict__ deg,
                                               int* __restrict__ bsum, int n)
{
  __shared__ int ws[4];
  const int t = threadIdx.x, lane = t & 63, wv = t >> 6;
  const int base = blockIdx.x * 1024 + t * 4;
  int4 v = make_int4(0, 0, 0, 0);
  if (base + 3 < n) v = *(const int4*)&deg[base];
  else {
    if (base + 0 < n) v.x = deg[base + 0];
    if (base + 1 < n) v.y = deg[base + 1];
    if (base + 2 < n) v.z = deg[base + 2];
  }
  int s = (v.x + v.y) + (v.z + v.w);
  #pragma unroll
  for (int off = 32; off; off >>= 1) s += __shfl_down(s, off, 64);
  if (lane == 0) ws[wv] = s;
  __syncthreads();
  if (t == 0) bsum[blockIdx.x] = (ws[0] + ws[1]) + (ws[2] + ws[3]);
}

__global__ __launch_bounds__(1024) void scan_p2(const int* __restrict__ bsum,
                                                int* __restrict__ boff,
                                                int* __restrict__ rowptr,
                                                int nb, int n)
{
  __shared__ int wsum[16], woff[16];
  const int t = threadIdx.x, lane = t & 63, wv = t >> 6;
  int v = (t < nb) ? bsum[t] : 0;
  int sc = v;
  #pragma unroll
  for (int off = 1; off < 64; off <<= 1) {
    int u = __shfl_up(sc, off, 64);
    if (lane >= off) sc += u;
  }
  if (lane == 63) wsum[wv] = sc;
  __syncthreads();
  if (t == 0) {
    int run = 0;
    #pragma unroll
    for (int i = 0; i < 16; ++i) { int x = wsum[i]; woff[i] = run; run += x; }
    rowptr[n] = run;
  }
  __syncthreads();
  if (t < nb) boff[t] = woff[wv] + sc - v;
}

__global__ __launch_bounds__(256) void scan_p3(const int* __restrict__ deg,
                                               const int* __restrict__ boff,
                                               int* __restrict__ rowptr,
                                               int* __restrict__ cursor, int n)
{
  __shared__ int wsum[4], woff[4];
  const int t = threadIdx.x, lane = t & 63, wv = t >> 6;
  const int base = blockIdx.x * 1024 + t * 4;
  int4 v = make_int4(0, 0, 0, 0);
  if (base + 3 < n) v = *(const int4*)&deg[base];
  else {
    if (base + 0 < n) v.x = deg[base + 0];
    if (base + 1 < n) v.y = deg[base + 1];
    if (base + 2 < n) v.z = deg[base + 2];
  }
  const int s = (v.x + v.y) + (v.z + v.w);
  int sc = s;
  #pragma unroll
  for (int off = 1; off < 64; off <<= 1) {
    int u = __shfl_up(sc, off, 64);
    if (lane >= off) sc += u;
  }
  if (lane == 63) wsum[wv] = sc;
  __syncthreads();
  if (t == 0) {
    int run = 0;
    #pragma unroll
    for (int i = 0; i < 4; ++i) { int x = wsum[i]; woff[i] = run; run += x; }
  }
  __syncthreads();
  int excl = boff[blockIdx.x] + woff[wv] + (sc - s);
  int4 r;
  r.x = excl;
  r.y = r.x + v.x;
  r.z = r.y + v.y;
  r.w = r.z + v.z;
  if (base + 3 < n) {
    *(int4*)&rowptr[base] = r;
    *(int4*)&cursor[base] = r;
  } else {
    if (base + 0 < n) { rowptr[base + 0] = r.x; cursor[base + 0] = r.x; }
    if (base + 1 < n) { rowptr[base + 1] = r.y; cursor[base + 1] = r.y; }
    if (base + 2 < n) { rowptr[base + 2] = r.z; cursor[base + 2] = r.z; }
  }
}

// ---------------------------------------------------------------------------
// D6: fill_csr, XCD-grouped, index-only (proven r5/r7/r8).
// ---------------------------------------------------------------------------
__global__ __launch_bounds__(256) void fill_csr(
    const int* __restrict__ ei, int* __restrict__ cursor,
    int* __restrict__ csr_src, int E, int nnodes)
{
  const int g    = blockIdx.x & 7;
  const int bg   = blockIdx.x >> 3;
  const int nbg  = gridDim.x >> 3;
  const int gsz  = (nnodes + 7) >> 3;
  const int dlo  = g * gsz;
  const int dhi  = min(dlo + gsz, nnodes);

  for (int e = bg * 256 + threadIdx.x; e < E; e += nbg * 256) {
    const int d = ei[E + e];
    if (d < dlo || d >= dhi) continue;
    const int pos = atomicAdd(&cursor[d], 1);
    csr_src[pos] = ei[e];
  }
}

// ---------------------------------------------------------------------------
// D7-D10: gather (proven r5/r7 logic), split into 4 QUARTER-RANGE dispatches.
// Purpose: diagnostic unmasking. Boundaries are ~free (r7<->r8 arithmetic),
// each quarter runs ~18us, so the top-5 will expose whichever hidden kernel
// (gemm_deg / fill_csr / deg path) is actually consuming the ~190us of
// non-gather time that has been invisible behind gather@72 since round 0.
// ---------------------------------------------------------------------------
__device__ __forceinline__ float4 ld_h(const unsigned short* __restrict__ h,
                                       int row, int cb)
{
  const ushort4 u = *(const ushort4*)&h[(size_t)row * 256 + cb];
  return make_float4(bf2f(u.x), bf2f(u.y), bf2f(u.z), bf2f(u.w));
}

__device__ __forceinline__ float edge_w(float as, float ad)
{
  float al = as + ad;
  al = al > 0.f ? al : NEG_SLOPE * al;
  return expf(al);
}

__global__ __launch_bounds__(256) void gather_kernel(
    const int* __restrict__ rowptr, const int* __restrict__ csr_src,
    const unsigned short* __restrict__ h,
    const float* __restrict__ a_src, const float* __restrict__ a_dst,
    const float* __restrict__ bias, float* __restrict__ out, int d0, int dend)
{
  const int wave = threadIdx.x >> 6;
  const int lane = threadIdx.x & 63;
  const int d = d0 + blockIdx.x * 4 + wave;
  if (d >= dend) return;

  const int head = lane >> 4;
  const int cb   = lane * 4;

  const float ad = a_dst[d * 4 + head];

  const float w = edge_w(a_src[d * 4 + head], ad);
  float dsum = w;
  float4 hv = ld_h(h, d, cb);
  float4 acc = make_float4(w * hv.x, w * hv.y, w * hv.z, w * hv.w);

  int j = rowptr[d];
  const int end = rowptr[d + 1];

  int4_t sC = {0, 0, 0, 0};
  if (j + 3 < end)
    sC = __builtin_nontemporal_load((const int4_t*)&csr_src[j]);
  while (j + 3 < end) {
    const int jn = j + 4;
    const int jp = (jn + 3 < end) ? jn : j;   // clamp: reload current on last iter
    const int4_t sN = __builtin_nontemporal_load((const int4_t*)&csr_src[jp]);

    const float as0 = a_src[sC.x * 4 + head];
    const float as1 = a_src[sC.y * 4 + head];
    const float as2 = a_src[sC.z * 4 + head];
    const float as3 = a_src[sC.w * 4 + head];
    const float4 h0 = ld_h(h, sC.x, cb);
    const float4 h1 = ld_h(h, sC.y, cb);
    const float4 h2 = ld_h(h, sC.z, cb);
    const float4 h3 = ld_h(h, sC.w, cb);

    const float w0 = edge_w(as0, ad);
    const float w1 = edge_w(as1, ad);
    const float w2 = edge_w(as2, ad);
    const float w3 = edge_w(as3, ad);

    dsum += (w0 + w1) + (w2 + w3);
    acc.x += w0 * h0.x + w1 * h1.x + w2 * h2.x + w3 * h3.x;
    acc.y += w0 * h0.y + w1 * h1.y + w2 * h2.y + w3 * h3.y;
    acc.z += w0 * h0.z + w1 * h1.z + w2 * h2.z + w3 * h3.z;
    acc.w += w0 * h0.w + w1 * h1.w + w2 * h2.w + w3 * h3.w;

    sC = sN; j = jn;
  }
  for (; j < end; ++j) {
    const int s0 = csr_src[j];
    const float w0 = edge_w(a_src[s0 * 4 + head], ad);
    const float4 h0 = ld_h(h, s0, cb);
    dsum += w0;
    acc.x += w0 * h0.x; acc.y += w0 * h0.y;
    acc.z += w0 * h0.z; acc.w += w0 * h0.w;
  }

  const float inv = 1.f / (dsum + 1e-16f);
  const float4 b4 = ((const float4*)bias)[lane];
  float4 o;
  o.x = acc.x * inv + b4.x; o.x = o.x > 0.f ? o.x : 0.f;
  o.y = acc.y * inv + b4.y; o.y = o.y > 0.f ? o.y : 0.f;
  o.z = acc.z * inv + b4.z; o.z = o.z > 0.f ? o.z : 0.f;
  o.w = acc.w * inv + b4.w; o.w = o.w > 0.f ? o.w : 0.f;
  *(float4*)&out[(size_t)d * 256 + cb] = o;
}

extern "C" void kernel_launch(void* const* d_in, const int* in_sizes, int n_in,
                              void* d_out, int out_size, void* d_ws, size_t ws_size,
                              hipStream_t stream)
{
  const float* x       = (const float*)d_in[0];
  const int*   ei      = (const int*)d_in[1];
  const float* W       = (const float*)d_in[2];
  const float* att_src = (const float*)d_in[3];
  const float* att_dst = (const float*)d_in[4];
  const float* bias    = (const float*)d_in[5];

  const int nnodes = in_sizes[0] / HC;   // 50000
  const int E      = in_sizes[1] / 2;    // 800000
  const int nb     = (nnodes + 1023) / 1024;   // 49

  float* out = (float*)d_out;
  char* ws = (char*)d_ws;
  // Workspace (~30 MB), all segments 16B-aligned:
  unsigned short* h  = (unsigned short*)ws;                          // nnodes*256 bf16 (row-major)
  float* a_src = (float*)(ws + (size_t)nnodes * HC * 2);             // nnodes*4 f32
  float* a_dst = a_src + (size_t)nnodes * 4;
  unsigned short* Wt = (unsigned short*)(a_dst + (size_t)nnodes * 4); // 256*256 bf16
  int* deg    = (int*)((char*)Wt + 256 * 256 * 2);                   // nnodes
  int* rowptr = deg + nnodes;                                        // nnodes+1 (pad x4)
  int* cursor = rowptr + ((nnodes + 1 + 3) & ~3);                    // nnodes
  int* bsum   = cursor + nnodes;                                     // nb
  int* boff   = bsum + ((nb + 3) & ~3);                              // nb
  int* csr    = boff + ((nb + 3) & ~3);                              // E

  const int NG = (nnodes + BM - 1) / BM;   // 782 gemm blocks
  const int ND = 1024;                     // histogram blocks

  wt_kernel<<<256, 256, 0, stream>>>(W, Wt, deg, nnodes);

  gemm_deg<<<NG + ND, 256, 0, stream>>>(
      x, Wt, att_src, att_dst, h, a_src, a_dst, nnodes, ei, deg, E, NG, ND);

  scan_p1<<<nb, 256, 0, stream>>>(deg, bsum, nnodes);
  scan_p2<<<1, 1024, 0, stream>>>(bsum, boff, rowptr, nb, nnodes);
  scan_p3<<<nb, 256, 0, stream>>>(deg, boff, rowptr, cursor, nnodes);

  fill_csr<<<1024, 256, 0, stream>>>(ei, cursor, csr, E, nnodes);

  // 4 quarter-range gather dispatches (diagnostic split; boundaries ~free)
  const int qn = (nnodes + 3) / 4;
  for (int qi = 0; qi < 4; ++qi) {
    const int d0   = qi * qn;
    const int dend = min(d0 + qn, nnodes);
    const int nblk = (dend - d0 + 3) / 4;
    if (nblk > 0)
      gather_kernel<<<nblk, 256, 0, stream>>>(
          rowptr, csr, h, a_src, a_dst, bias, out, d0, dend);
  }
}

// Round 10
// 258.945 us; speedup vs baseline: 1.4325x; 1.1196x over previous
//
#include <hip/hip_runtime.h>
#include <hip/hip_bf16.h>

#define HC 256        // HEADS*OUT_CH
#define NEG_SLOPE 0.2f
#define BM 64
#define LDKF 264      // full-k padded LDS stride (bf16 elems): 528B rows, 16B-aligned

typedef short short8_t __attribute__((ext_vector_type(8)));
typedef float float4_t __attribute__((ext_vector_type(4)));
typedef int   int4_t   __attribute__((ext_vector_type(4)));

__device__ __forceinline__ unsigned short f2bf(float f) {
  unsigned u = __float_as_uint(f);
  return (unsigned short)((u + 0x7fffu + ((u >> 16) & 1u)) >> 16);  // RNE
}
__device__ __forceinline__ float bf2f(unsigned short b) {
  return __uint_as_float(((unsigned)b) << 16);
}

// ---------------------------------------------------------------------------
// D1: Wq = W packed into MFMA B-FRAGMENT ORDER + zero deg.
// Wq[((wv*4+nt)*8+kstep)*64 + l][j] = bf16( W[kstep*32+(l>>4)*8+j][64wv+16nt+(l&15)] )
// so the gemm's B-load is 64 lanes x 16B CONTIGUOUS (1KB/instr) instead of a
// 64-line 512B-stride scatter (r9 counters: gemm latency-bound, all pipes idle).
// ---------------------------------------------------------------------------
__global__ __launch_bounds__(256) void wq_kernel(
    const float* __restrict__ W, unsigned short* __restrict__ Wq,
    int* __restrict__ deg, int n)
{
  const int f = blockIdx.x * 256 + threadIdx.x;   // 65536 threads
  if (f < 8192) {                                  // 8192 fragments of 8 bf16
    const int wv    = f >> 11;
    const int nt    = (f >> 9) & 3;
    const int kstep = (f >> 6) & 7;
    const int l     = f & 63;
    const int ncol  = 64 * wv + 16 * nt + (l & 15);
    const int k0    = kstep * 32 + (l >> 4) * 8;
    unsigned pk[4];
    #pragma unroll
    for (int i = 0; i < 4; ++i) {
      __hip_bfloat162 b2 = __float22bfloat162_rn(make_float2(
          W[(k0 + 2 * i) * 256 + ncol], W[(k0 + 2 * i + 1) * 256 + ncol]));
      pk[i] = *(unsigned*)&b2;
    }
    *(uint4*)&Wq[(size_t)f * 8] = make_uint4(pk[0], pk[1], pk[2], pk[3]);
  }
  if (f < n) deg[f] = 0;
}

// ---------------------------------------------------------------------------
// D2: FUSED gemm + deg histogram.  GEMM changes vs r9:
//  * B from fragment-packed Wq: fully coalesced 1KB wave loads (L2-hot).
//  * MFMA operands SWAPPED: D = Wq-frag x As-frag -> lane owns node=(l&15),
//    4 CONSECUTIVE channels (4q+reg). h-store: one 8B store per (mt,nt)
//    (16 stores/thread vs 64x 2B scatter). att reduction: in-thread dot
//    over 16 channels + 2 shfl over q-groups.
// ---------------------------------------------------------------------------
__global__ __launch_bounds__(256) void gemm_deg(
    const float* __restrict__ x, const unsigned short* __restrict__ Wq,
    const float* __restrict__ att_src, const float* __restrict__ att_dst,
    unsigned short* __restrict__ h, float* __restrict__ a_src,
    float* __restrict__ a_dst, int nnodes,
    const int* __restrict__ ei, int* __restrict__ deg, int E, int NG, int ND)
{
  __shared__ unsigned short As[BM * LDKF];   // 33792 B (gemm path only)
  const int t = threadIdx.x;

  if (blockIdx.x >= NG) {
    // ---- histogram path ----
    const int b = blockIdx.x - NG;
    for (int e = b * 256 + t; e < E; e += ND * 256)
      atomicAdd(&deg[ei[E + e]], 1);
    return;
  }

  // ---- gemm path ----
  const int wv   = t >> 6;
  const int lane = t & 63;
  const int r0   = blockIdx.x * BM;

  // stage full A tile (64 rows x 256 k) as bf16, one pass (proven r7-r9)
  {
    const int row = t >> 2, kcb = (t & 3) * 16;
    const int gr = r0 + row;
    #pragma unroll
    for (int k0 = 0; k0 < 256; k0 += 64) {
      float4 xv[4];
      if (gr < nnodes) {
        const float4* p = (const float4*)(x + (size_t)gr * 256 + k0 + kcb);
        xv[0] = p[0]; xv[1] = p[1]; xv[2] = p[2]; xv[3] = p[3];
      } else {
        xv[0] = xv[1] = xv[2] = xv[3] = make_float4(0.f, 0.f, 0.f, 0.f);
      }
      const float* f = (const float*)xv;
      unsigned pk[8];
      #pragma unroll
      for (int i = 0; i < 8; ++i) {
        __hip_bfloat162 b2 = __float22bfloat162_rn(make_float2(f[2 * i], f[2 * i + 1]));
        pk[i] = *(unsigned*)&b2;
      }
      uint4* d = (uint4*)&As[row * LDKF + k0 + kcb];
      d[0] = make_uint4(pk[0], pk[1], pk[2], pk[3]);
      d[1] = make_uint4(pk[4], pk[5], pk[6], pk[7]);
    }
  }
  __syncthreads();

  const int l15 = lane & 15, q = lane >> 4;
  float4_t acc[4][4] = {};   // [mt=node-tile][nt=channel-tile]

  // Wq base for this wave+lane: + nt*4096 + kstep*512 (units: shorts)
  const unsigned short* __restrict__ Bq = Wq + (size_t)wv * 16384 + lane * 8;

  #pragma unroll
  for (int kstep = 0; kstep < 8; ++kstep) {
    const int ko = kstep * 32;
    short8_t bfr[4], af[4];
    #pragma unroll
    for (int nt = 0; nt < 4; ++nt)
      bfr[nt] = *(const short8_t*)(Bq + nt * 4096 + kstep * 512);
    #pragma unroll
    for (int mt = 0; mt < 4; ++mt)
      af[mt] = *(const short8_t*)&As[(16 * mt + l15) * LDKF + ko + q * 8];
    #pragma unroll
    for (int mt = 0; mt < 4; ++mt)
      #pragma unroll
      for (int nt = 0; nt < 4; ++nt)
        acc[mt][nt] = __builtin_amdgcn_mfma_f32_16x16x32_bf16(
            bfr[nt], af[mt], acc[mt][nt], 0, 0, 0);   // SWAPPED operands
  }

  // epilogue: lane owns node = r0+16mt+l15, channels 64wv+16nt+4q+{0..3}
  float4 as4[4], ad4[4];
  #pragma unroll
  for (int nt = 0; nt < 4; ++nt) {
    as4[nt] = *(const float4*)&att_src[64 * wv + 16 * nt + 4 * q];
    ad4[nt] = *(const float4*)&att_dst[64 * wv + 16 * nt + 4 * q];
  }

  #pragma unroll
  for (int mt = 0; mt < 4; ++mt) {
    const int node = r0 + 16 * mt + l15;
    const bool ok = node < nnodes;
    float ps = 0.f, pd = 0.f;
    #pragma unroll
    for (int nt = 0; nt < 4; ++nt) {
      const float4_t v = acc[mt][nt];
      if (ok) {
        __hip_bfloat162 b01 = __float22bfloat162_rn(make_float2(v[0], v[1]));
        __hip_bfloat162 b23 = __float22bfloat162_rn(make_float2(v[2], v[3]));
        uint2 u = make_uint2(*(unsigned*)&b01, *(unsigned*)&b23);
        *(uint2*)&h[(size_t)node * 256 + 64 * wv + 16 * nt + 4 * q] = u;  // 8B store
      }
      ps += v[0] * as4[nt].x + v[1] * as4[nt].y + v[2] * as4[nt].z + v[3] * as4[nt].w;
      pd += v[0] * ad4[nt].x + v[1] * ad4[nt].y + v[2] * ad4[nt].z + v[3] * ad4[nt].w;
    }
    // reduce across the 4 q-groups (lanes l15, l15+16, l15+32, l15+48)
    ps += __shfl_down(ps, 16); ps += __shfl_down(ps, 32);
    pd += __shfl_down(pd, 16); pd += __shfl_down(pd, 32);
    if (ok && lane < 16) {
      a_src[node * 4 + wv] = ps;
      a_dst[node * 4 + wv] = pd;
    }
  }
}

// ---------------------------------------------------------------------------
// D3-D5: 3-phase scan (proven r7/r9).
// ---------------------------------------------------------------------------
__global__ __launch_bounds__(256) void scan_p1(const int* __restrict__ deg,
                                               int* __restrict__ bsum, int n)
{
  __shared__ int ws[4];
  const int t = threadIdx.x, lane = t & 63, wv = t >> 6;
  const int base = blockIdx.x * 1024 + t * 4;
  int4 v = make_int4(0, 0, 0, 0);
  if (base + 3 < n) v = *(const int4*)&deg[base];
  else {
    if (base + 0 < n) v.x = deg[base + 0];
    if (base + 1 < n) v.y = deg[base + 1];
    if (base + 2 < n) v.z = deg[base + 2];
  }
  int s = (v.x + v.y) + (v.z + v.w);
  #pragma unroll
  for (int off = 32; off; off >>= 1) s += __shfl_down(s, off, 64);
  if (lane == 0) ws[wv] = s;
  __syncthreads();
  if (t == 0) bsum[blockIdx.x] = (ws[0] + ws[1]) + (ws[2] + ws[3]);
}

__global__ __launch_bounds__(1024) void scan_p2(const int* __restrict__ bsum,
                                                int* __restrict__ boff,
                                                int* __restrict__ rowptr,
                                                int nb, int n)
{
  __shared__ int wsum[16], woff[16];
  const int t = threadIdx.x, lane = t & 63, wv = t >> 6;
  int v = (t < nb) ? bsum[t] : 0;
  int sc = v;
  #pragma unroll
  for (int off = 1; off < 64; off <<= 1) {
    int u = __shfl_up(sc, off, 64);
    if (lane >= off) sc += u;
  }
  if (lane == 63) wsum[wv] = sc;
  __syncthreads();
  if (t == 0) {
    int run = 0;
    #pragma unroll
    for (int i = 0; i < 16; ++i) { int x = wsum[i]; woff[i] = run; run += x; }
    rowptr[n] = run;
  }
  __syncthreads();
  if (t < nb) boff[t] = woff[wv] + sc - v;
}

__global__ __launch_bounds__(256) void scan_p3(const int* __restrict__ deg,
                                               const int* __restrict__ boff,
                                               int* __restrict__ rowptr,
                                               int* __restrict__ cursor, int n)
{
  __shared__ int wsum[4], woff[4];
  const int t = threadIdx.x, lane = t & 63, wv = t >> 6;
  const int base = blockIdx.x * 1024 + t * 4;
  int4 v = make_int4(0, 0, 0, 0);
  if (base + 3 < n) v = *(const int4*)&deg[base];
  else {
    if (base + 0 < n) v.x = deg[base + 0];
    if (base + 1 < n) v.y = deg[base + 1];
    if (base + 2 < n) v.z = deg[base + 2];
  }
  const int s = (v.x + v.y) + (v.z + v.w);
  int sc = s;
  #pragma unroll
  for (int off = 1; off < 64; off <<= 1) {
    int u = __shfl_up(sc, off, 64);
    if (lane >= off) sc += u;
  }
  if (lane == 63) wsum[wv] = sc;
  __syncthreads();
  if (t == 0) {
    int run = 0;
    #pragma unroll
    for (int i = 0; i < 4; ++i) { int x = wsum[i]; woff[i] = run; run += x; }
  }
  __syncthreads();
  int excl = boff[blockIdx.x] + woff[wv] + (sc - s);
  int4 r;
  r.x = excl;
  r.y = r.x + v.x;
  r.z = r.y + v.y;
  r.w = r.z + v.z;
  if (base + 3 < n) {
    *(int4*)&rowptr[base] = r;
    *(int4*)&cursor[base] = r;
  } else {
    if (base + 0 < n) { rowptr[base + 0] = r.x; cursor[base + 0] = r.x; }
    if (base + 1 < n) { rowptr[base + 1] = r.y; cursor[base + 1] = r.y; }
    if (base + 2 < n) { rowptr[base + 2] = r.z; cursor[base + 2] = r.z; }
  }
}

// ---------------------------------------------------------------------------
// D6: fill_csr, XCD-grouped, index-only (proven r5/r7/r9).
// ---------------------------------------------------------------------------
__global__ __launch_bounds__(256) void fill_csr(
    const int* __restrict__ ei, int* __restrict__ cursor,
    int* __restrict__ csr_src, int E, int nnodes)
{
  const int g    = blockIdx.x & 7;
  const int bg   = blockIdx.x >> 3;
  const int nbg  = gridDim.x >> 3;
  const int gsz  = (nnodes + 7) >> 3;
  const int dlo  = g * gsz;
  const int dhi  = min(dlo + gsz, nnodes);

  for (int e = bg * 256 + threadIdx.x; e < E; e += nbg * 256) {
    const int d = ei[E + e];
    if (d < dlo || d >= dhi) continue;
    const int pos = atomicAdd(&cursor[d], 1);
    csr_src[pos] = ei[e];
  }
}

// ---------------------------------------------------------------------------
// D7: gather — single full-range dispatch (proven r5/r7; quarters cost ~10us).
// ---------------------------------------------------------------------------
__device__ __forceinline__ float4 ld_h(const unsigned short* __restrict__ h,
                                       int row, int cb)
{
  const ushort4 u = *(const ushort4*)&h[(size_t)row * 256 + cb];
  return make_float4(bf2f(u.x), bf2f(u.y), bf2f(u.z), bf2f(u.w));
}

__device__ __forceinline__ float edge_w(float as, float ad)
{
  float al = as + ad;
  al = al > 0.f ? al : NEG_SLOPE * al;
  return expf(al);
}

__global__ __launch_bounds__(256) void gather_kernel(
    const int* __restrict__ rowptr, const int* __restrict__ csr_src,
    const unsigned short* __restrict__ h,
    const float* __restrict__ a_src, const float* __restrict__ a_dst,
    const float* __restrict__ bias, float* __restrict__ out, int n)
{
  const int wave = threadIdx.x >> 6;
  const int lane = threadIdx.x & 63;
  const int d = blockIdx.x * 4 + wave;
  if (d >= n) return;

  const int head = lane >> 4;
  const int cb   = lane * 4;

  const float ad = a_dst[d * 4 + head];

  const float w = edge_w(a_src[d * 4 + head], ad);
  float dsum = w;
  float4 hv = ld_h(h, d, cb);
  float4 acc = make_float4(w * hv.x, w * hv.y, w * hv.z, w * hv.w);

  int j = rowptr[d];
  const int end = rowptr[d + 1];

  int4_t sC = {0, 0, 0, 0};
  if (j + 3 < end)
    sC = __builtin_nontemporal_load((const int4_t*)&csr_src[j]);
  while (j + 3 < end) {
    const int jn = j + 4;
    const int jp = (jn + 3 < end) ? jn : j;   // clamp: reload current on last iter
    const int4_t sN = __builtin_nontemporal_load((const int4_t*)&csr_src[jp]);

    const float as0 = a_src[sC.x * 4 + head];
    const float as1 = a_src[sC.y * 4 + head];
    const float as2 = a_src[sC.z * 4 + head];
    const float as3 = a_src[sC.w * 4 + head];
    const float4 h0 = ld_h(h, sC.x, cb);
    const float4 h1 = ld_h(h, sC.y, cb);
    const float4 h2 = ld_h(h, sC.z, cb);
    const float4 h3 = ld_h(h, sC.w, cb);

    const float w0 = edge_w(as0, ad);
    const float w1 = edge_w(as1, ad);
    const float w2 = edge_w(as2, ad);
    const float w3 = edge_w(as3, ad);

    dsum += (w0 + w1) + (w2 + w3);
    acc.x += w0 * h0.x + w1 * h1.x + w2 * h2.x + w3 * h3.x;
    acc.y += w0 * h0.y + w1 * h1.y + w2 * h2.y + w3 * h3.y;
    acc.z += w0 * h0.z + w1 * h1.z + w2 * h2.z + w3 * h3.z;
    acc.w += w0 * h0.w + w1 * h1.w + w2 * h2.w + w3 * h3.w;

    sC = sN; j = jn;
  }
  for (; j < end; ++j) {
    const int s0 = csr_src[j];
    const float w0 = edge_w(a_src[s0 * 4 + head], ad);
    const float4 h0 = ld_h(h, s0, cb);
    dsum += w0;
    acc.x += w0 * h0.x; acc.y += w0 * h0.y;
    acc.z += w0 * h0.z; acc.w += w0 * h0.w;
  }

  const float inv = 1.f / (dsum + 1e-16f);
  const float4 b4 = ((const float4*)bias)[lane];
  float4 o;
  o.x = acc.x * inv + b4.x; o.x = o.x > 0.f ? o.x : 0.f;
  o.y = acc.y * inv + b4.y; o.y = o.y > 0.f ? o.y : 0.f;
  o.z = acc.z * inv + b4.z; o.z = o.z > 0.f ? o.z : 0.f;
  o.w = acc.w * inv + b4.w; o.w = o.w > 0.f ? o.w : 0.f;
  *(float4*)&out[(size_t)d * 256 + cb] = o;
}

extern "C" void kernel_launch(void* const* d_in, const int* in_sizes, int n_in,
                              void* d_out, int out_size, void* d_ws, size_t ws_size,
                              hipStream_t stream)
{
  const float* x       = (const float*)d_in[0];
  const int*   ei      = (const int*)d_in[1];
  const float* W       = (const float*)d_in[2];
  const float* att_src = (const float*)d_in[3];
  const float* att_dst = (const float*)d_in[4];
  const float* bias    = (const float*)d_in[5];

  const int nnodes = in_sizes[0] / HC;   // 50000
  const int E      = in_sizes[1] / 2;    // 800000
  const int nb     = (nnodes + 1023) / 1024;   // 49

  float* out = (float*)d_out;
  char* ws = (char*)d_ws;
  // Workspace (~30 MB), all segments 16B-aligned:
  unsigned short* h  = (unsigned short*)ws;                          // nnodes*256 bf16 (row-major)
  float* a_src = (float*)(ws + (size_t)nnodes * HC * 2);             // nnodes*4 f32
  float* a_dst = a_src + (size_t)nnodes * 4;
  unsigned short* Wq = (unsigned short*)(a_dst + (size_t)nnodes * 4); // 256*256 bf16 (fragment order)
  int* deg    = (int*)((char*)Wq + 256 * 256 * 2);                   // nnodes
  int* rowptr = deg + nnodes;                                        // nnodes+1 (pad x4)
  int* cursor = rowptr + ((nnodes + 1 + 3) & ~3);                    // nnodes
  int* bsum   = cursor + nnodes;                                     // nb
  int* boff   = bsum + ((nb + 3) & ~3);                              // nb
  int* csr    = boff + ((nb + 3) & ~3);                              // E

  const int NG = (nnodes + BM - 1) / BM;   // 782 gemm blocks
  const int ND = 1024;                     // histogram blocks

  wq_kernel<<<256, 256, 0, stream>>>(W, Wq, deg, nnodes);

  gemm_deg<<<NG + ND, 256, 0, stream>>>(
      x, Wq, att_src, att_dst, h, a_src, a_dst, nnodes, ei, deg, E, NG, ND);

  scan_p1<<<nb, 256, 0, stream>>>(deg, bsum, nnodes);
  scan_p2<<<1, 1024, 0, stream>>>(bsum, boff, rowptr, nb, nnodes);
  scan_p3<<<nb, 256, 0, stream>>>(deg, boff, rowptr, cursor, nnodes);

  fill_csr<<<1024, 256, 0, stream>>>(ei, cursor, csr, E, nnodes);

  gather_kernel<<<(nnodes + 3) / 4, 256, 0, stream>>>(
      rowptr, csr, h, a_src, a_dst, bias, out, nnodes);
}